// Round 6
// baseline (112.711 us; speedup 1.0000x reference)
//
#include <hip/hip_runtime.h>
#include <hip/hip_bf16.h>

// E=1024, H=16, P=64, B=2, S=2048. All f32 in/out.
// Pipeline (algebra verified rounds 1-5, absmax <= 0.5):
//   WpT[zp][j] = sum_d proj_w[d][p] * Wz[j][d]  -> bf16 hi/lo planes [192][1024]
//   q,k,v      = x @ Wp + bias; q -> bf16 planes; k,v stay in-block
//   Mpart[rb]  = k_tile^T v_tile (64-row chunk, computed inside qkv3)
//   Meff[b]    = 0.125*(c<32?1:-lam)*sum_rb Mpart ; lam,Weff computed in gkern3
//   G[b]       = Meff @ Weff -> GT bf16 planes [b][1024 e][64 c]
//   out[b]     = Q @ G via MFMA
// Split-bf16 MFMA: A*B ~= Ahi*Bhi + Ahi*Blo + Alo*Bhi (rel err ~1e-4).

typedef __attribute__((ext_vector_type(8))) short short8;
typedef __attribute__((ext_vector_type(4))) float f32x4;
typedef unsigned short ushort_t;
typedef unsigned int uint_t;

__device__ inline ushort_t f2bf(float v) {
    uint_t u = __float_as_uint(v);
    return (ushort_t)((u + 0x7FFF + ((u >> 16) & 1)) >> 16);   // RNE
}
__device__ inline float bf2f(ushort_t h) { return __uint_as_float(((uint_t)h) << 16); }
__device__ inline void split2(float v, ushort_t& hi, ushort_t& lo) {
    hi = f2bf(v);
    lo = f2bf(v - bf2f(hi));
}
__device__ inline int swzA(int row, int k) { return (row * 64 + k) ^ ((row & 7) << 3); }

// ---- K1: WpT planes. grid 48 = z(3) x jblk(16). Full-K, in-LDS transpose of proj_w.
__global__ __launch_bounds__(256) void prep3(
    const float* __restrict__ WQ, const float* __restrict__ WK, const float* __restrict__ WV,
    const float* __restrict__ proj_w,
    ushort_t* __restrict__ WpThi, ushort_t* __restrict__ WpTlo)
{
    __shared__ __align__(16) char smem[50176];
    float (*At)[68] = (float(*)[68])smem;              // 17408 B (f32 staging of proj_w chunk)
    ushort_t* Ah = (ushort_t*)(smem + 17408);
    ushort_t* Al = (ushort_t*)(smem + 25600);
    ushort_t* Bh = (ushort_t*)(smem + 33792);
    ushort_t* Bl = (ushort_t*)(smem + 41984);

    int bid = blockIdx.x, tid = threadIdx.x;
    int z = bid >> 4, jblk = bid & 15;
    const float* Wz = (z == 0) ? WQ : (z == 1) ? WK : WV;
    long long j0 = (long long)jblk * 64;
    int wave = tid >> 6, lane = tid & 63, rl = lane & 15, kg = lane >> 4;
    f32x4 acc[4] = {};

    float4 av[4], bv0[4], bv1[4];
    #pragma unroll
    for (int i = 0; i < 4; ++i) {
        int pos = tid + 256 * i;
        int r = pos >> 4, c4 = (pos & 15) * 4;
        av[i]  = *(const float4*)&proj_w[(long long)r * 64 + c4];
        bv0[i] = *(const float4*)&Wz[(j0 + r) * 1024 + c4];
        bv1[i] = *(const float4*)&Wz[(j0 + r) * 1024 + 64 + c4];
    }

    for (int ch = 0; ch < 16; ++ch) {
        // stage: At f32 (vector), B planes (split, vector)
        #pragma unroll
        for (int i = 0; i < 4; ++i) {
            int pos = tid + 256 * i;
            int r = pos >> 4, c4 = (pos & 15) * 4;
            *(float4*)&At[r][c4] = av[i];
            ushort4 h, l;
            split2(bv0[i].x, h.x, l.x); split2(bv0[i].y, h.y, l.y);
            split2(bv0[i].z, h.z, l.z); split2(bv0[i].w, h.w, l.w);
            int idx = swzA(r, c4);
            *(ushort4*)&Bh[idx] = h;
            *(ushort4*)&Bl[idx] = l;
        }
        __syncthreads();
        // prefetch next (av depth-1, bv depth-2)
        #pragma unroll
        for (int i = 0; i < 4; ++i) {
            int pos = tid + 256 * i;
            int r = pos >> 4, c4 = (pos & 15) * 4;
            if (ch < 15) av[i] = *(const float4*)&proj_w[(long long)((ch + 1) * 64 + r) * 64 + c4];
            bv0[i] = bv1[i];
            if (ch < 14) bv1[i] = *(const float4*)&Wz[(j0 + r) * 1024 + (ch + 2) * 64 + c4];
        }
        // transpose-build A planes: Ah[swz(p,d)] = proj_w[d0+d][p]
        #pragma unroll
        for (int i = 0; i < 2; ++i) {
            int pos = tid + 256 * i;
            int p = pos & 63, d8 = pos >> 6;    // d8 in 0..7
            short8 h8, l8;
            #pragma unroll
            for (int t = 0; t < 8; ++t) {
                ushort_t hh, ll;
                split2(At[d8 * 8 + t][p], hh, ll);
                h8[t] = (short)hh; l8[t] = (short)ll;
            }
            int idx = swzA(p, d8 * 8);
            *(short8*)&Ah[idx] = h8;
            *(short8*)&Al[idx] = l8;
        }
        __syncthreads();
        // MFMA
        int ar = wave * 16 + rl;
        #pragma unroll
        for (int ks = 0; ks < 2; ++ks) {
            int kb = ks * 32 + kg * 8;
            short8 ah = *(const short8*)&Ah[swzA(ar, kb)];
            short8 al = *(const short8*)&Al[swzA(ar, kb)];
            #pragma unroll
            for (int n = 0; n < 4; ++n) {
                int bi = swzA(n * 16 + rl, kb);
                short8 bh = *(const short8*)&Bh[bi];
                short8 bl = *(const short8*)&Bl[bi];
                acc[n] = __builtin_amdgcn_mfma_f32_16x16x32_bf16(ah, bh, acc[n], 0, 0, 0);
                acc[n] = __builtin_amdgcn_mfma_f32_16x16x32_bf16(ah, bl, acc[n], 0, 0, 0);
                acc[n] = __builtin_amdgcn_mfma_f32_16x16x32_bf16(al, bh, acc[n], 0, 0, 0);
            }
        }
        __builtin_amdgcn_s_barrier();
    }
    // epilogue: C[p][j] = WpT[z*64+p][j0+j]
    #pragma unroll
    for (int n = 0; n < 4; ++n) {
        long long jcol = j0 + n * 16 + rl;
        #pragma unroll
        for (int j = 0; j < 4; ++j) {
            int prow = wave * 16 + kg * 4 + j;
            ushort_t h, l; split2(acc[n][j], h, l);
            long long idx = (long long)(z * 64 + prow) * 1024 + jcol;
            WpThi[idx] = h; WpTlo[idx] = l;
        }
    }
}

// ---- K2: q,k,v + in-block Mpart. grid 128: bid<64 -> q-kind, else kv-kind.
__global__ __launch_bounds__(256) void qkv3(
    const float* __restrict__ x,
    const ushort_t* __restrict__ WpThi, const ushort_t* __restrict__ WpTlo,
    const float* __restrict__ proj_b,
    ushort_t* __restrict__ Qhi, ushort_t* __restrict__ Qlo,
    float* __restrict__ Mpart)
{
    __shared__ __align__(16) char smem[49152];
    ushort_t* Ah  = (ushort_t*)(smem);
    ushort_t* Al  = (ushort_t*)(smem + 8192);
    ushort_t* B1h = (ushort_t*)(smem + 16384);
    ushort_t* B1l = (ushort_t*)(smem + 24576);
    ushort_t* B2h = (ushort_t*)(smem + 32768);
    ushort_t* B2l = (ushort_t*)(smem + 40960);
    float (*ksh)[68] = (float(*)[68])(smem);            // aliased post-loop
    float (*vsh)[68] = (float(*)[68])(smem + 17408);

    int bid = blockIdx.x, tid = threadIdx.x;
    int kv = bid >> 6, rowblk = bid & 63;
    long long row0 = (long long)rowblk * 64;
    int wave = tid >> 6, lane = tid & 63, rl = lane & 15, kg = lane >> 4;
    int zb1 = kv ? 64 : 0;

    f32x4 acc1[4] = {}, acc2[4] = {};
    float4 av0[4], av1[4];
    short8 p1h[2], p1l[2], p2h[2], p2l[2];

    #pragma unroll
    for (int i = 0; i < 4; ++i) {
        int pos = tid + 256 * i;
        int r = pos >> 4, c4 = (pos & 15) * 4;
        av0[i] = *(const float4*)&x[(row0 + r) * 1024 + c4];
        av1[i] = *(const float4*)&x[(row0 + r) * 1024 + 64 + c4];
    }
    #pragma unroll
    for (int i = 0; i < 2; ++i) {
        int pos = tid + 256 * i;
        int n = pos >> 3, k8 = (pos & 7) * 8;
        p1h[i] = *(const short8*)&WpThi[(long long)(zb1 + n) * 1024 + k8];
        p1l[i] = *(const short8*)&WpTlo[(long long)(zb1 + n) * 1024 + k8];
        if (kv) {
            p2h[i] = *(const short8*)&WpThi[(long long)(128 + n) * 1024 + k8];
            p2l[i] = *(const short8*)&WpTlo[(long long)(128 + n) * 1024 + k8];
        }
    }

    for (int ch = 0; ch < 16; ++ch) {
        #pragma unroll
        for (int i = 0; i < 4; ++i) {
            int pos = tid + 256 * i;
            int r = pos >> 4, c4 = (pos & 15) * 4;
            ushort4 h, l;
            split2(av0[i].x, h.x, l.x); split2(av0[i].y, h.y, l.y);
            split2(av0[i].z, h.z, l.z); split2(av0[i].w, h.w, l.w);
            int idx = swzA(r, c4);
            *(ushort4*)&Ah[idx] = h;
            *(ushort4*)&Al[idx] = l;
        }
        #pragma unroll
        for (int i = 0; i < 2; ++i) {
            int pos = tid + 256 * i;
            int n = pos >> 3, k8 = (pos & 7) * 8;
            int idx = swzA(n, k8);
            *(short8*)&B1h[idx] = p1h[i];
            *(short8*)&B1l[idx] = p1l[i];
            if (kv) {
                *(short8*)&B2h[idx] = p2h[i];
                *(short8*)&B2l[idx] = p2l[i];
            }
        }
        __syncthreads();
        // prefetch (x depth-2, planes depth-1)
        #pragma unroll
        for (int i = 0; i < 4; ++i) {
            int pos = tid + 256 * i;
            int r = pos >> 4, c4 = (pos & 15) * 4;
            av0[i] = av1[i];
            if (ch < 14) av1[i] = *(const float4*)&x[(row0 + r) * 1024 + (ch + 2) * 64 + c4];
        }
        if (ch < 15) {
            int k0n = (ch + 1) * 64;
            #pragma unroll
            for (int i = 0; i < 2; ++i) {
                int pos = tid + 256 * i;
                int n = pos >> 3, k8 = (pos & 7) * 8;
                p1h[i] = *(const short8*)&WpThi[(long long)(zb1 + n) * 1024 + k0n + k8];
                p1l[i] = *(const short8*)&WpTlo[(long long)(zb1 + n) * 1024 + k0n + k8];
                if (kv) {
                    p2h[i] = *(const short8*)&WpThi[(long long)(128 + n) * 1024 + k0n + k8];
                    p2l[i] = *(const short8*)&WpTlo[(long long)(128 + n) * 1024 + k0n + k8];
                }
            }
        }
        int ar = wave * 16 + rl;
        #pragma unroll
        for (int ks = 0; ks < 2; ++ks) {
            int kb = ks * 32 + kg * 8;
            short8 ah = *(const short8*)&Ah[swzA(ar, kb)];
            short8 al = *(const short8*)&Al[swzA(ar, kb)];
            #pragma unroll
            for (int n = 0; n < 4; ++n) {
                int bi = swzA(n * 16 + rl, kb);
                short8 bh = *(const short8*)&B1h[bi];
                short8 bl = *(const short8*)&B1l[bi];
                acc1[n] = __builtin_amdgcn_mfma_f32_16x16x32_bf16(ah, bh, acc1[n], 0, 0, 0);
                acc1[n] = __builtin_amdgcn_mfma_f32_16x16x32_bf16(ah, bl, acc1[n], 0, 0, 0);
                acc1[n] = __builtin_amdgcn_mfma_f32_16x16x32_bf16(al, bh, acc1[n], 0, 0, 0);
                if (kv) {
                    short8 ch2 = *(const short8*)&B2h[bi];
                    short8 cl2 = *(const short8*)&B2l[bi];
                    acc2[n] = __builtin_amdgcn_mfma_f32_16x16x32_bf16(ah, ch2, acc2[n], 0, 0, 0);
                    acc2[n] = __builtin_amdgcn_mfma_f32_16x16x32_bf16(ah, cl2, acc2[n], 0, 0, 0);
                    acc2[n] = __builtin_amdgcn_mfma_f32_16x16x32_bf16(al, ch2, acc2[n], 0, 0, 0);
                }
            }
        }
        __builtin_amdgcn_s_barrier();
    }

    if (!kv) {
        #pragma unroll
        for (int n = 0; n < 4; ++n) {
            int col = n * 16 + rl;
            float bb = proj_b[col];
            #pragma unroll
            for (int j = 0; j < 4; ++j) {
                long long row = row0 + wave * 16 + kg * 4 + j;
                ushort_t h, l; split2(acc1[n][j] + bb, h, l);
                Qhi[row * 64 + col] = h;
                Qlo[row * 64 + col] = l;
            }
        }
    } else {
        // write k,v tiles to LDS (aliases plane buffers; loop closed with s_barrier)
        #pragma unroll
        for (int n = 0; n < 4; ++n) {
            int col = n * 16 + rl;
            float bb = proj_b[col];
            #pragma unroll
            for (int j = 0; j < 4; ++j) {
                int r = wave * 16 + kg * 4 + j;
                ksh[r][col] = acc1[n][j] + bb;
                vsh[r][col] = acc2[n][j] + bb;
            }
        }
        __syncthreads();
        int p = tid & 63, cg = tid >> 6;
        float macc[16] = {};
        for (int s = 0; s < 64; ++s) {
            float vv = vsh[s][p];
            float4 k0 = *(const float4*)&ksh[s][cg * 16];
            float4 k1 = *(const float4*)&ksh[s][cg * 16 + 4];
            float4 k2 = *(const float4*)&ksh[s][cg * 16 + 8];
            float4 k3 = *(const float4*)&ksh[s][cg * 16 + 12];
            macc[0] += k0.x * vv;  macc[1] += k0.y * vv;  macc[2] += k0.z * vv;  macc[3] += k0.w * vv;
            macc[4] += k1.x * vv;  macc[5] += k1.y * vv;  macc[6] += k1.z * vv;  macc[7] += k1.w * vv;
            macc[8] += k2.x * vv;  macc[9] += k2.y * vv;  macc[10] += k2.z * vv; macc[11] += k2.w * vv;
            macc[12] += k3.x * vv; macc[13] += k3.y * vv; macc[14] += k3.z * vv; macc[15] += k3.w * vv;
        }
        float* o = Mpart + (long long)rowblk * 4096;
        #pragma unroll
        for (int ci = 0; ci < 16; ++ci)
            o[(cg * 16 + ci) * 64 + p] = macc[ci];
    }
}

// ---- K3: lam + Weff-slice + Meff reduce + G GEMM -> GT planes. grid 32.
__global__ __launch_bounds__(256) void gkern3(
    const float* __restrict__ Mpart, const float* __restrict__ RW,
    const float* __restrict__ q1v, const float* __restrict__ k1v,
    const float* __restrict__ q2v, const float* __restrict__ k2v,
    const float* __restrict__ lam0,
    ushort_t* __restrict__ GThi, ushort_t* __restrict__ GTlo)
{
    int colblk = blockIdx.x & 15, b = blockIdx.x >> 4;
    __shared__ float As[64][68], Bs[64][68];
    __shared__ float red[2][4];
    int tid = threadIdx.x;

    // lam (block-local)
    float d1 = 0.f, d2 = 0.f;
    for (int i = tid; i < 1024; i += 256) {
        d1 += q1v[i] * k1v[i];
        d2 += q2v[i] * k2v[i];
    }
    #pragma unroll
    for (int off = 32; off > 0; off >>= 1) {
        d1 += __shfl_down(d1, off);
        d2 += __shfl_down(d2, off);
    }
    if ((tid & 63) == 0) { red[0][tid >> 6] = d1; red[1][tid >> 6] = d2; }
    __syncthreads();
    float s1 = red[0][0] + red[0][1] + red[0][2] + red[0][3];
    float s2 = red[1][0] + red[1][1] + red[1][2] + red[1][3];
    float lam = expf(s1) - expf(s2) + lam0[0];

    // As = Meff[b] (reduce 32 rowblk chunks, fold coef)
    #pragma unroll
    for (int i = 0; i < 4; ++i) {
        int pos = tid + 256 * i;
        int c = pos >> 4, p4 = (pos & 15) * 4;
        float4 s = {0.f, 0.f, 0.f, 0.f};
        #pragma unroll 8
        for (int sc = 0; sc < 32; ++sc) {
            float4 m = *(const float4*)&Mpart[(long long)(b * 32 + sc) * 4096 + c * 64 + p4];
            s.x += m.x; s.y += m.y; s.z += m.z; s.w += m.w;
        }
        float coef = 0.125f * (c < 32 ? 1.0f : -lam);
        s.x *= coef; s.y *= coef; s.z *= coef; s.w *= coef;
        *(float4*)&As[c][p4] = s;
    }
    // Bs = Weff slice [64 p][64 e]
    #pragma unroll
    for (int i = 0; i < 4; ++i) {
        int pos = tid + 256 * i;
        int p = pos >> 4, e4 = (pos & 15) * 4;
        float4 s = {0.f, 0.f, 0.f, 0.f};
        #pragma unroll
        for (int h = 0; h < 16; ++h) {
            float4 r = *(const float4*)&RW[(long long)(h * 64 + p) * 1024 + colblk * 64 + e4];
            float m = (float)(h + 1);
            s.x += m * r.x; s.y += m * r.y; s.z += m * r.z; s.w += m * r.w;
        }
        *(float4*)&Bs[p][e4] = s;
    }
    __syncthreads();

    int tx = tid & 15, ty = tid >> 4;
    float acc[4][4] = {};
    #pragma unroll 4
    for (int kk4 = 0; kk4 < 64; kk4 += 4) {
        float4 a4[4], b4[4];
        #pragma unroll
        for (int i = 0; i < 4; ++i) a4[i] = *(const float4*)&As[ty * 4 + i][kk4];
        #pragma unroll
        for (int r = 0; r < 4; ++r) b4[r] = *(const float4*)&Bs[kk4 + r][tx * 4];
        #pragma unroll
        for (int i = 0; i < 4; ++i) {
            acc[i][0] += a4[i].x * b4[0].x + a4[i].y * b4[1].x + a4[i].z * b4[2].x + a4[i].w * b4[3].x;
            acc[i][1] += a4[i].x * b4[0].y + a4[i].y * b4[1].y + a4[i].z * b4[2].y + a4[i].w * b4[3].y;
            acc[i][2] += a4[i].x * b4[0].z + a4[i].y * b4[1].z + a4[i].z * b4[2].z + a4[i].w * b4[3].z;
            acc[i][3] += a4[i].x * b4[0].w + a4[i].y * b4[1].w + a4[i].z * b4[2].w + a4[i].w * b4[3].w;
        }
    }
    #pragma unroll
    for (int i = 0; i < 4; ++i)
        #pragma unroll
        for (int j = 0; j < 4; ++j) {
            ushort_t h, l; split2(acc[i][j], h, l);
            long long idx = (long long)b * 65536 + (long long)(colblk * 64 + tx * 4 + j) * 64 + ty * 4 + i;
            GThi[idx] = h; GTlo[idx] = l;
        }
}

// ---- K4: out = Q @ G. grid 1024.
__global__ __launch_bounds__(256) void outk(
    const ushort_t* __restrict__ Qhi, const ushort_t* __restrict__ Qlo,
    const ushort_t* __restrict__ GThi, const ushort_t* __restrict__ GTlo,
    float* __restrict__ out)
{
    __shared__ __align__(16) ushort_t Ah[4096], Al[4096], Bh[4096], Bl[4096];
    int bid = blockIdx.x;
    int rowblk = bid & 31, colblk = (bid >> 5) & 15, b = bid >> 9;
    int tid = threadIdx.x;
    long long row0 = (long long)b * 2048 + rowblk * 64;

    #pragma unroll
    for (int i = 0; i < 2; ++i) {
        int pos = tid + 256 * i;
        int n = pos >> 3, k8 = (pos & 7) * 8;
        int idx = swzA(n, k8);
        long long qsrc = (row0 + n) * 64 + k8;
        long long gsrc = (long long)b * 65536 + (long long)(colblk * 64 + n) * 64 + k8;
        *(short8*)&Ah[idx] = *(const short8*)&Qhi[qsrc];
        *(short8*)&Al[idx] = *(const short8*)&Qlo[qsrc];
        *(short8*)&Bh[idx] = *(const short8*)&GThi[gsrc];
        *(short8*)&Bl[idx] = *(const short8*)&GTlo[gsrc];
    }
    __syncthreads();

    int wave = tid >> 6, lane = tid & 63;
    int rl = lane & 15, kg = lane >> 4;
    f32x4 acc[4] = {};
    int ar = wave * 16 + rl;
    #pragma unroll
    for (int ks = 0; ks < 2; ++ks) {
        int kb = ks * 32 + kg * 8;
        short8 ah = *(const short8*)&Ah[swzA(ar, kb)];
        short8 al = *(const short8*)&Al[swzA(ar, kb)];
        #pragma unroll
        for (int n = 0; n < 4; ++n) {
            int bi = swzA(n * 16 + rl, kb);
            short8 bh = *(const short8*)&Bh[bi];
            short8 bl = *(const short8*)&Bl[bi];
            acc[n] = __builtin_amdgcn_mfma_f32_16x16x32_bf16(ah, bh, acc[n], 0, 0, 0);
            acc[n] = __builtin_amdgcn_mfma_f32_16x16x32_bf16(ah, bl, acc[n], 0, 0, 0);
            acc[n] = __builtin_amdgcn_mfma_f32_16x16x32_bf16(al, bh, acc[n], 0, 0, 0);
        }
    }
    #pragma unroll
    for (int n = 0; n < 4; ++n) {
        int col = colblk * 64 + n * 16 + rl;
        #pragma unroll
        for (int j = 0; j < 4; ++j) {
            int row = rowblk * 64 + wave * 16 + kg * 4 + j;
            out[(long long)b * 2097152 + (long long)row * 1024 + col] = acc[n][j];
        }
    }
}

extern "C" void kernel_launch(void* const* d_in, const int* in_sizes, int n_in,
                              void* d_out, int out_size, void* d_ws, size_t ws_size,
                              hipStream_t stream)
{
    const float* x      = (const float*)d_in[0];
    const float* WQ     = (const float*)d_in[1];
    const float* WK     = (const float*)d_in[2];
    const float* WV     = (const float*)d_in[3];
    const float* RW     = (const float*)d_in[4];
    const float* proj_w = (const float*)d_in[5];
    const float* proj_b = (const float*)d_in[6];
    const float* q1v    = (const float*)d_in[7];
    const float* k1v    = (const float*)d_in[8];
    const float* q2v    = (const float*)d_in[9];
    const float* k2v    = (const float*)d_in[10];
    const float* lam0   = (const float*)d_in[11];
    float* out = (float*)d_out;

    float* ws    = (float*)d_ws;
    float* Mpart = ws;                          // 64*4096 = 262144 f32
    ushort_t* ub = (ushort_t*)(ws + 262144);
    ushort_t* WpThi = ub;                       // 196608
    ushort_t* WpTlo = ub + 196608;
    ushort_t* Qhi   = ub + 393216;              // 262144
    ushort_t* Qlo   = ub + 655360;
    ushort_t* GThi  = ub + 917504;              // 131072
    ushort_t* GTlo  = ub + 1048576;

    dim3 blk(256);
    prep3<<<dim3(48), blk, 0, stream>>>(WQ, WK, WV, proj_w, WpThi, WpTlo);
    qkv3<<<dim3(128), blk, 0, stream>>>(x, WpThi, WpTlo, proj_b, Qhi, Qlo, Mpart);
    gkern3<<<dim3(32), blk, 0, stream>>>(Mpart, RW, q1v, k1v, q2v, k2v, lam0, GThi, GTlo);
    outk<<<dim3(1024), blk, 0, stream>>>(Qhi, Qlo, GThi, GTlo, out);
}

// Round 7
// 70.340 us; speedup vs baseline: 1.6024x; 1.6024x over previous
//
#include <hip/hip_runtime.h>
#include <hip/hip_bf16.h>

// E=1024, H=16, P=64, B=2, S=2048. All f32 in/out.
// Pipeline (algebra verified rounds 1-6, absmax <= 0.5):
//   Wp = [WQ|WK|WV] @ proj_w  (split-K x8 MFMA partials, stored TRANSPOSED)
//   WpT planes = coalesced reduce of 8 slices -> bf16 hi/lo [192][1024]
//   q,k,v = x @ Wp + bias  (full-K per block; q -> bf16 planes, k/v -> f32)
//   Mpart = per-32-row-chunk k^T v
//   gkern3: lam + Weff-slice (from RW) + Meff reduce + G GEMM -> GT planes
//   out[b] = Q @ G via MFMA
// Split-bf16 MFMA: A*B ~= Ahi*Bhi + Ahi*Blo + Alo*Bhi (rel err ~1e-4).

typedef __attribute__((ext_vector_type(8))) short short8;
typedef __attribute__((ext_vector_type(4))) float f32x4;
typedef unsigned short ushort_t;
typedef unsigned int uint_t;

__device__ inline ushort_t f2bf(float v) {
    uint_t u = __float_as_uint(v);
    return (ushort_t)((u + 0x7FFF + ((u >> 16) & 1)) >> 16);   // RNE
}
__device__ inline float bf2f(ushort_t h) { return __uint_as_float(((uint_t)h) << 16); }
__device__ inline void split2(float v, ushort_t& hi, ushort_t& lo) {
    hi = f2bf(v);
    lo = f2bf(v - bf2f(hi));
}
__device__ inline int swzA(int row, int k) { return (row * 64 + k) ^ ((row & 7) << 3); }

// ---- K1: Wp split-K partials, stored transposed. grid 384 = slice(8) x z(3) x rowblk(16)
__global__ __launch_bounds__(256) void prep_sk(
    const float* __restrict__ WQ, const float* __restrict__ WK, const float* __restrict__ WV,
    const float* __restrict__ proj_w, float* __restrict__ wppartT)
{
    __shared__ __align__(16) ushort_t Ah[4096], Al[4096], Bh[4096], Bl[4096];
    int bid = blockIdx.x;
    int slice = bid / 48, t = bid % 48, z = t / 16, rowblk = t % 16;
    const float* A = ((z == 0) ? WQ : (z == 1) ? WK : WV) + (long long)rowblk * 64 * 1024;

    int tid = threadIdx.x;
    int wave = tid >> 6, lane = tid & 63;
    int rl = lane & 15, kg = lane >> 4;
    f32x4 acc[4] = {};

    int k0 = slice * 128;
    for (int ch = 0; ch < 2; ++ch, k0 += 64) {
        #pragma unroll
        for (int i = 0; i < 4; ++i) {
            int pos = tid + 256 * i;
            int r = pos >> 4, k4 = (pos & 15) * 4;
            float4 v = *(const float4*)&A[(long long)r * 1024 + k0 + k4];
            ushort4 h, l;
            split2(v.x, h.x, l.x); split2(v.y, h.y, l.y);
            split2(v.z, h.z, l.z); split2(v.w, h.w, l.w);
            int idx = swzA(r, k4);
            *(ushort4*)&Ah[idx] = h;
            *(ushort4*)&Al[idx] = l;
        }
        // B = proj_w chunk [64 k][64 n], split + transpose into [n][k]
        #pragma unroll
        for (int i = 0; i < 4; ++i) {
            int pos = tid + 256 * i;
            int kk = pos >> 4, n4 = (pos & 15) * 4;
            float4 v = *(const float4*)&proj_w[(long long)(k0 + kk) * 64 + n4];
            float vv[4] = {v.x, v.y, v.z, v.w};
            #pragma unroll
            for (int j = 0; j < 4; ++j) {
                ushort_t h, l; split2(vv[j], h, l);
                int idx = swzA(n4 + j, kk);
                Bh[idx] = h; Bl[idx] = l;
            }
        }
        __syncthreads();
        int ar = wave * 16 + rl;
        #pragma unroll
        for (int ks = 0; ks < 2; ++ks) {
            int kb = ks * 32 + kg * 8;
            short8 ah = *(const short8*)&Ah[swzA(ar, kb)];
            short8 al = *(const short8*)&Al[swzA(ar, kb)];
            #pragma unroll
            for (int n = 0; n < 4; ++n) {
                int bi = swzA(n * 16 + rl, kb);
                short8 bh = *(const short8*)&Bh[bi];
                short8 bl = *(const short8*)&Bl[bi];
                acc[n] = __builtin_amdgcn_mfma_f32_16x16x32_bf16(ah, bh, acc[n], 0, 0, 0);
                acc[n] = __builtin_amdgcn_mfma_f32_16x16x32_bf16(ah, bl, acc[n], 0, 0, 0);
                acc[n] = __builtin_amdgcn_mfma_f32_16x16x32_bf16(al, bh, acc[n], 0, 0, 0);
            }
        }
        __syncthreads();
    }
    // transposed store: wppartT[slice][(z*64 + col)][rowblk*64 + row], j contiguous
    #pragma unroll
    for (int n = 0; n < 4; ++n) {
        int col = n * 16 + rl;
        float4 o = {acc[n][0], acc[n][1], acc[n][2], acc[n][3]};
        long long idx = (long long)slice * 196608 + (long long)(z * 64 + col) * 1024
                      + rowblk * 64 + wave * 16 + kg * 4;
        *(float4*)&wppartT[idx] = o;
    }
}

// ---- K2: reduce 8 slices -> WpT bf16 planes (fully coalesced). grid 192.
__global__ __launch_bounds__(256) void wpfix2(
    const float* __restrict__ wppartT,
    ushort_t* __restrict__ WpThi, ushort_t* __restrict__ WpTlo)
{
    int idx = blockIdx.x * 256 + threadIdx.x;   // 49152 f4-units over [192][1024]
    long long off = (long long)idx * 4;
    float4 s = {0.f, 0.f, 0.f, 0.f};
    #pragma unroll
    for (int sl = 0; sl < 8; ++sl) {
        float4 m = *(const float4*)&wppartT[(long long)sl * 196608 + off];
        s.x += m.x; s.y += m.y; s.z += m.z; s.w += m.w;
    }
    ushort4 h, l;
    split2(s.x, h.x, l.x); split2(s.y, h.y, l.y);
    split2(s.z, h.z, l.z); split2(s.w, h.w, l.w);
    *(ushort4*)&WpThi[off] = h;
    *(ushort4*)&WpTlo[off] = l;
}

// ---- K3: q,k,v full-K per block. grid 192 = z(3) x rowblk(64).
__global__ __launch_bounds__(256) void qkv2(
    const float* __restrict__ x,
    const ushort_t* __restrict__ WpThi, const ushort_t* __restrict__ WpTlo,
    const float* __restrict__ proj_b,
    ushort_t* __restrict__ Qhi, ushort_t* __restrict__ Qlo,
    float* __restrict__ kbuf, float* __restrict__ vbuf)
{
    __shared__ __align__(16) ushort_t Ah[4096], Al[4096], Bh[4096], Bl[4096];
    int bid = blockIdx.x, tid = threadIdx.x;
    int z = bid >> 6, rowblk = bid & 63;
    long long row0 = (long long)rowblk * 64;
    int wave = tid >> 6, lane = tid & 63, rl = lane & 15, kg = lane >> 4;
    f32x4 acc[4] = {};
    float4 av[4];
    short8 pbh[2], pbl[2];
    #pragma unroll
    for (int i = 0; i < 4; ++i) {
        int pos = tid + 256 * i;
        int r = pos >> 4, c4 = (pos & 15) * 4;
        av[i] = *(const float4*)&x[(row0 + r) * 1024 + c4];
    }
    #pragma unroll
    for (int i = 0; i < 2; ++i) {
        int pos = tid + 256 * i;
        int n = pos >> 3, k8 = (pos & 7) * 8;
        long long src = (long long)(z * 64 + n) * 1024 + k8;
        pbh[i] = *(const short8*)&WpThi[src];
        pbl[i] = *(const short8*)&WpTlo[src];
    }
    for (int ch = 0; ch < 16; ++ch) {
        #pragma unroll
        for (int i = 0; i < 4; ++i) {
            int pos = tid + 256 * i;
            int r = pos >> 4, c4 = (pos & 15) * 4;
            ushort4 h, l;
            split2(av[i].x, h.x, l.x); split2(av[i].y, h.y, l.y);
            split2(av[i].z, h.z, l.z); split2(av[i].w, h.w, l.w);
            int idx = swzA(r, c4);
            *(ushort4*)&Ah[idx] = h;
            *(ushort4*)&Al[idx] = l;
        }
        #pragma unroll
        for (int i = 0; i < 2; ++i) {
            int pos = tid + 256 * i;
            int n = pos >> 3, k8 = (pos & 7) * 8;
            int idx = swzA(n, k8);
            *(short8*)&Bh[idx] = pbh[i];
            *(short8*)&Bl[idx] = pbl[i];
        }
        __syncthreads();
        if (ch < 15) {
            int k0 = (ch + 1) * 64;
            #pragma unroll
            for (int i = 0; i < 4; ++i) {
                int pos = tid + 256 * i;
                int r = pos >> 4, c4 = (pos & 15) * 4;
                av[i] = *(const float4*)&x[(row0 + r) * 1024 + k0 + c4];
            }
            #pragma unroll
            for (int i = 0; i < 2; ++i) {
                int pos = tid + 256 * i;
                int n = pos >> 3, k8 = (pos & 7) * 8;
                long long src = (long long)(z * 64 + n) * 1024 + k0 + k8;
                pbh[i] = *(const short8*)&WpThi[src];
                pbl[i] = *(const short8*)&WpTlo[src];
            }
        }
        int ar = wave * 16 + rl;
        #pragma unroll
        for (int ks = 0; ks < 2; ++ks) {
            int kb = ks * 32 + kg * 8;
            short8 ah = *(const short8*)&Ah[swzA(ar, kb)];
            short8 al = *(const short8*)&Al[swzA(ar, kb)];
            #pragma unroll
            for (int n = 0; n < 4; ++n) {
                int bi = swzA(n * 16 + rl, kb);
                short8 bh = *(const short8*)&Bh[bi];
                short8 bl = *(const short8*)&Bl[bi];
                acc[n] = __builtin_amdgcn_mfma_f32_16x16x32_bf16(ah, bh, acc[n], 0, 0, 0);
                acc[n] = __builtin_amdgcn_mfma_f32_16x16x32_bf16(ah, bl, acc[n], 0, 0, 0);
                acc[n] = __builtin_amdgcn_mfma_f32_16x16x32_bf16(al, bh, acc[n], 0, 0, 0);
            }
        }
        __builtin_amdgcn_s_barrier();
    }
    #pragma unroll
    for (int n = 0; n < 4; ++n) {
        int col = n * 16 + rl;
        float bb = proj_b[col];
        #pragma unroll
        for (int j = 0; j < 4; ++j) {
            long long row = row0 + wave * 16 + kg * 4 + j;
            float val = acc[n][j] + bb;
            if (z == 0) {
                ushort_t h, l; split2(val, h, l);
                Qhi[row * 64 + col] = h;
                Qlo[row * 64 + col] = l;
            } else if (z == 1) {
                kbuf[row * 64 + col] = val;
            } else {
                vbuf[row * 64 + col] = val;
            }
        }
    }
}

// ---- K4: Mpart[b][sc][c][p] over 32-row chunks. grid 128 = sc(64) x b(2).
__global__ __launch_bounds__(256) void mpart2(
    const float* __restrict__ kbuf, const float* __restrict__ vbuf,
    float* __restrict__ Mpart)
{
    int bid = blockIdx.x;
    int sc = bid & 63, b = bid >> 6;
    __shared__ float ksh[32][68], vsh[32][68];
    int tid = threadIdx.x;
    long long row0 = (long long)b * 2048 + sc * 32;
    #pragma unroll
    for (int i = 0; i < 4; ++i) {
        int pos = tid + 256 * i;        // 1024: arr(2) x r(32) x c4(16)
        int arr = pos >> 9, rem = pos & 511;
        int r = rem >> 4, c4 = (rem & 15) * 4;
        const float* src = (arr ? vbuf : kbuf) + (row0 + r) * 64 + c4;
        float4 v = *(const float4*)src;
        if (arr == 0) *(float4*)&ksh[r][c4] = v;
        else          *(float4*)&vsh[r][c4] = v;
    }
    __syncthreads();
    int p = tid & 63, cg = tid >> 6;
    float acc[16] = {};
    for (int s = 0; s < 32; ++s) {
        float vv = vsh[s][p];
        float4 k0 = *(const float4*)&ksh[s][cg * 16];
        float4 k1 = *(const float4*)&ksh[s][cg * 16 + 4];
        float4 k2 = *(const float4*)&ksh[s][cg * 16 + 8];
        float4 k3 = *(const float4*)&ksh[s][cg * 16 + 12];
        acc[0] += k0.x * vv;  acc[1] += k0.y * vv;  acc[2] += k0.z * vv;  acc[3] += k0.w * vv;
        acc[4] += k1.x * vv;  acc[5] += k1.y * vv;  acc[6] += k1.z * vv;  acc[7] += k1.w * vv;
        acc[8] += k2.x * vv;  acc[9] += k2.y * vv;  acc[10] += k2.z * vv; acc[11] += k2.w * vv;
        acc[12] += k3.x * vv; acc[13] += k3.y * vv; acc[14] += k3.z * vv; acc[15] += k3.w * vv;
    }
    float* o = Mpart + ((long long)b * 64 + sc) * 4096;
    #pragma unroll
    for (int ci = 0; ci < 16; ++ci)
        o[(cg * 16 + ci) * 64 + p] = acc[ci];
}

// ---- K5: lam + Weff-slice + Meff reduce + G GEMM -> GT planes. grid 32.
__global__ __launch_bounds__(256) void gkern3(
    const float* __restrict__ Mpart, const float* __restrict__ RW,
    const float* __restrict__ q1v, const float* __restrict__ k1v,
    const float* __restrict__ q2v, const float* __restrict__ k2v,
    const float* __restrict__ lam0,
    ushort_t* __restrict__ GThi, ushort_t* __restrict__ GTlo)
{
    int colblk = blockIdx.x & 15, b = blockIdx.x >> 4;
    __shared__ float As[64][68], Bs[64][68];
    __shared__ float red[2][4];
    int tid = threadIdx.x;

    float d1 = 0.f, d2 = 0.f;
    for (int i = tid; i < 1024; i += 256) {
        d1 += q1v[i] * k1v[i];
        d2 += q2v[i] * k2v[i];
    }
    #pragma unroll
    for (int off = 32; off > 0; off >>= 1) {
        d1 += __shfl_down(d1, off);
        d2 += __shfl_down(d2, off);
    }
    if ((tid & 63) == 0) { red[0][tid >> 6] = d1; red[1][tid >> 6] = d2; }
    __syncthreads();
    float s1 = red[0][0] + red[0][1] + red[0][2] + red[0][3];
    float s2 = red[1][0] + red[1][1] + red[1][2] + red[1][3];
    float lam = expf(s1) - expf(s2) + lam0[0];

    // As = Meff[b] (reduce 64 chunks of 32 rows, fold coef)
    #pragma unroll
    for (int i = 0; i < 4; ++i) {
        int pos = tid + 256 * i;
        int c = pos >> 4, p4 = (pos & 15) * 4;
        float4 s = {0.f, 0.f, 0.f, 0.f};
        #pragma unroll 8
        for (int sc = 0; sc < 64; ++sc) {
            float4 m = *(const float4*)&Mpart[((long long)b * 64 + sc) * 4096 + c * 64 + p4];
            s.x += m.x; s.y += m.y; s.z += m.z; s.w += m.w;
        }
        float coef = 0.125f * (c < 32 ? 1.0f : -lam);
        s.x *= coef; s.y *= coef; s.z *= coef; s.w *= coef;
        *(float4*)&As[c][p4] = s;
    }
    // Bs = Weff slice [64 p][64 e]
    #pragma unroll
    for (int i = 0; i < 4; ++i) {
        int pos = tid + 256 * i;
        int p = pos >> 4, e4 = (pos & 15) * 4;
        float4 s = {0.f, 0.f, 0.f, 0.f};
        #pragma unroll
        for (int h = 0; h < 16; ++h) {
            float4 r = *(const float4*)&RW[(long long)(h * 64 + p) * 1024 + colblk * 64 + e4];
            float m = (float)(h + 1);
            s.x += m * r.x; s.y += m * r.y; s.z += m * r.z; s.w += m * r.w;
        }
        *(float4*)&Bs[p][e4] = s;
    }
    __syncthreads();

    int tx = tid & 15, ty = tid >> 4;
    float acc[4][4] = {};
    #pragma unroll 4
    for (int kk4 = 0; kk4 < 64; kk4 += 4) {
        float4 a4[4], b4[4];
        #pragma unroll
        for (int i = 0; i < 4; ++i) a4[i] = *(const float4*)&As[ty * 4 + i][kk4];
        #pragma unroll
        for (int r = 0; r < 4; ++r) b4[r] = *(const float4*)&Bs[kk4 + r][tx * 4];
        #pragma unroll
        for (int i = 0; i < 4; ++i) {
            acc[i][0] += a4[i].x * b4[0].x + a4[i].y * b4[1].x + a4[i].z * b4[2].x + a4[i].w * b4[3].x;
            acc[i][1] += a4[i].x * b4[0].y + a4[i].y * b4[1].y + a4[i].z * b4[2].y + a4[i].w * b4[3].y;
            acc[i][2] += a4[i].x * b4[0].z + a4[i].y * b4[1].z + a4[i].z * b4[2].z + a4[i].w * b4[3].z;
            acc[i][3] += a4[i].x * b4[0].w + a4[i].y * b4[1].w + a4[i].z * b4[2].w + a4[i].w * b4[3].w;
        }
    }
    #pragma unroll
    for (int i = 0; i < 4; ++i)
        #pragma unroll
        for (int j = 0; j < 4; ++j) {
            ushort_t h, l; split2(acc[i][j], h, l);
            long long idx = (long long)b * 65536 + (long long)(colblk * 64 + tx * 4 + j) * 64 + ty * 4 + i;
            GThi[idx] = h; GTlo[idx] = l;
        }
}

// ---- K6: out = Q @ G. grid 1024.
__global__ __launch_bounds__(256) void outk(
    const ushort_t* __restrict__ Qhi, const ushort_t* __restrict__ Qlo,
    const ushort_t* __restrict__ GThi, const ushort_t* __restrict__ GTlo,
    float* __restrict__ out)
{
    __shared__ __align__(16) ushort_t Ah[4096], Al[4096], Bh[4096], Bl[4096];
    int bid = blockIdx.x;
    int rowblk = bid & 31, colblk = (bid >> 5) & 15, b = bid >> 9;
    int tid = threadIdx.x;
    long long row0 = (long long)b * 2048 + rowblk * 64;

    #pragma unroll
    for (int i = 0; i < 2; ++i) {
        int pos = tid + 256 * i;
        int n = pos >> 3, k8 = (pos & 7) * 8;
        int idx = swzA(n, k8);
        long long qsrc = (row0 + n) * 64 + k8;
        long long gsrc = (long long)b * 65536 + (long long)(colblk * 64 + n) * 64 + k8;
        *(short8*)&Ah[idx] = *(const short8*)&Qhi[qsrc];
        *(short8*)&Al[idx] = *(const short8*)&Qlo[qsrc];
        *(short8*)&Bh[idx] = *(const short8*)&GThi[gsrc];
        *(short8*)&Bl[idx] = *(const short8*)&GTlo[gsrc];
    }
    __syncthreads();

    int wave = tid >> 6, lane = tid & 63;
    int rl = lane & 15, kg = lane >> 4;
    f32x4 acc[4] = {};
    int ar = wave * 16 + rl;
    #pragma unroll
    for (int ks = 0; ks < 2; ++ks) {
        int kb = ks * 32 + kg * 8;
        short8 ah = *(const short8*)&Ah[swzA(ar, kb)];
        short8 al = *(const short8*)&Al[swzA(ar, kb)];
        #pragma unroll
        for (int n = 0; n < 4; ++n) {
            int bi = swzA(n * 16 + rl, kb);
            short8 bh = *(const short8*)&Bh[bi];
            short8 bl = *(const short8*)&Bl[bi];
            acc[n] = __builtin_amdgcn_mfma_f32_16x16x32_bf16(ah, bh, acc[n], 0, 0, 0);
            acc[n] = __builtin_amdgcn_mfma_f32_16x16x32_bf16(ah, bl, acc[n], 0, 0, 0);
            acc[n] = __builtin_amdgcn_mfma_f32_16x16x32_bf16(al, bh, acc[n], 0, 0, 0);
        }
    }
    #pragma unroll
    for (int n = 0; n < 4; ++n) {
        int col = colblk * 64 + n * 16 + rl;
        #pragma unroll
        for (int j = 0; j < 4; ++j) {
            int row = rowblk * 64 + wave * 16 + kg * 4 + j;
            out[(long long)b * 2097152 + (long long)row * 1024 + col] = acc[n][j];
        }
    }
}

extern "C" void kernel_launch(void* const* d_in, const int* in_sizes, int n_in,
                              void* d_out, int out_size, void* d_ws, size_t ws_size,
                              hipStream_t stream)
{
    const float* x      = (const float*)d_in[0];
    const float* WQ     = (const float*)d_in[1];
    const float* WK     = (const float*)d_in[2];
    const float* WV     = (const float*)d_in[3];
    const float* RW     = (const float*)d_in[4];
    const float* proj_w = (const float*)d_in[5];
    const float* proj_b = (const float*)d_in[6];
    const float* q1v    = (const float*)d_in[7];
    const float* k1v    = (const float*)d_in[8];
    const float* q2v    = (const float*)d_in[9];
    const float* k2v    = (const float*)d_in[10];
    const float* lam0   = (const float*)d_in[11];
    float* out = (float*)d_out;

    float* ws       = (float*)d_ws;
    float* wppartT  = ws;                       // 8*196608 = 1,572,864
    float* kbuf     = ws + 1572864;             // 262,144
    float* vbuf     = ws + 1835008;             // 262,144
    float* Mpart    = ws + 2097152;             // 524,288
    ushort_t* ub    = (ushort_t*)(ws + 2621440);
    ushort_t* WpThi = ub;                       // 196,608
    ushort_t* WpTlo = ub + 196608;
    ushort_t* Qhi   = ub + 393216;              // 262,144
    ushort_t* Qlo   = ub + 655360;
    ushort_t* GThi  = ub + 917504;              // 131,072
    ushort_t* GTlo  = ub + 1048576;

    dim3 blk(256);
    prep_sk<<<dim3(384), blk, 0, stream>>>(WQ, WK, WV, proj_w, wppartT);
    wpfix2<<<dim3(192), blk, 0, stream>>>(wppartT, WpThi, WpTlo);
    qkv2<<<dim3(192), blk, 0, stream>>>(x, WpThi, WpTlo, proj_b, Qhi, Qlo, kbuf, vbuf);
    mpart2<<<dim3(128), blk, 0, stream>>>(kbuf, vbuf, Mpart);
    gkern3<<<dim3(32), blk, 0, stream>>>(Mpart, RW, q1v, k1v, q2v, k2v, lam0, GThi, GTlo);
    outk<<<dim3(1024), blk, 0, stream>>>(Qhi, Qlo, GThi, GTlo, out);
}